// Round 7
// baseline (234.634 us; speedup 1.0000x reference)
//
#include <hip/hip_runtime.h>
#include <hip/hip_bf16.h>

// ---------------------------------------------------------------------------
// SingleLayerMoE: T=1024 tokens, H=1024, E=8 experts, I=1024, top-2 routing.
// R6: k_prep converts gup/dp to bf16 TRANSPOSED [e][col][k] (LDS-tile
//     transpose, xor-swizzled, ~144 MB streaming). GEMM B staging becomes
//     pure uint4 copies (no cvt, uniform LDS banks). BM=128 tiles halve
//     weight re-fetch. down fuses combine via atomicAdd into out (router
//     pre-writes weighted bias). 5 launches: memset/router/prep/gateup/down.
// ---------------------------------------------------------------------------

typedef unsigned short u16;
typedef __attribute__((ext_vector_type(8))) __bf16 bf16x8;
typedef __attribute__((ext_vector_type(4))) float f32x4;

#define T_TOK 1024
#define H_DIM 1024
#define E_NUM 8
#define I_DIM 1024
#define ALPHA 1.702f
#define LIMIT 7.0f
#define LSTR 72                 // u16 row stride: uniform bank spread on b128 ops
#define AROWS 2176              // act rows incl slack (abase+cnt+126 max)

__device__ __forceinline__ u16 f2bf(float f) {
    unsigned u = __builtin_bit_cast(unsigned, f);
    u = (u + 0x7FFFu + ((u >> 16) & 1u)) >> 16;
    return (u16)u;
}

__device__ __forceinline__ unsigned pk2(float lo, float hi) {
#if defined(__has_builtin) && __has_builtin(__builtin_amdgcn_cvt_pk_bf16_f32)
    typedef __attribute__((ext_vector_type(2))) __bf16 bf16x2_t;
    bf16x2_t v = __builtin_amdgcn_cvt_pk_bf16_f32(lo, hi);
    return __builtin_bit_cast(unsigned, v);
#else
    return (unsigned)f2bf(lo) | ((unsigned)f2bf(hi) << 16);
#endif
}

__device__ __forceinline__ f32x4 mfma16(bf16x8 a, bf16x8 b, f32x4 c) {
    return __builtin_amdgcn_mfma_f32_16x16x32_bf16(a, b, c, 0, 0, 0);
}

__device__ __forceinline__ void expert_range(const int* counts, int e,
                                             int& cnt, int& abase) {
    int a = 0, c = 0;
#pragma unroll
    for (int i = 0; i < E_NUM; ++i) {
        int v = counts[i];
        if (i < e) a += v;
        if (i == e) c = v;
    }
    cnt = c; abase = a;
}

// ------------- K1: router + dispatch + x->bf16 + weighted-bias out ----------
__global__ __launch_bounds__(256) void k_router(
    const float* __restrict__ x, const float* __restrict__ rw,
    const float* __restrict__ rb, const float* __restrict__ db,
    int* __restrict__ counts, int* __restrict__ tok_list,
    float* __restrict__ w_list, u16* __restrict__ xb,
    float* __restrict__ out)
{
    const int t = blockIdx.x;
    const int tid = threadIdx.x;
    const float4 xv = *(const float4*)(x + (size_t)t * H_DIM + tid * 4);

    *(uint2*)(xb + (size_t)t * H_DIM + tid * 4) =
        make_uint2(pk2(xv.x, xv.y), pk2(xv.z, xv.w));

    float p[E_NUM];
#pragma unroll
    for (int e = 0; e < E_NUM; ++e) {
        const float4 wv = *(const float4*)(rw + e * H_DIM + tid * 4);
        p[e] = xv.x * wv.x + xv.y * wv.y + xv.z * wv.z + xv.w * wv.w;
    }
#pragma unroll
    for (int off = 32; off; off >>= 1) {
#pragma unroll
        for (int e = 0; e < E_NUM; ++e) p[e] += __shfl_down(p[e], off, 64);
    }
    __shared__ float red[4][E_NUM];
    __shared__ int se[2];
    __shared__ float sw[2];
    const int lane = tid & 63, wvid = tid >> 6;
    if (lane == 0) {
#pragma unroll
        for (int e = 0; e < E_NUM; ++e) red[wvid][e] = p[e];
    }
    __syncthreads();
    if (tid == 0) {
        float lg[E_NUM];
#pragma unroll
        for (int e = 0; e < E_NUM; ++e)
            lg[e] = red[0][e] + red[1][e] + red[2][e] + red[3][e] + rb[e];
        float m1 = -1e30f, m2 = -1e30f; int i1 = 0, i2 = 0;
#pragma unroll
        for (int e = 0; e < E_NUM; ++e) {
            float l = lg[e];
            if (l > m1) { m2 = m1; i2 = i1; m1 = l; i1 = e; }
            else if (l > m2) { m2 = l; i2 = e; }
        }
        float s = 0.f;
#pragma unroll
        for (int e = 0; e < E_NUM; ++e) s += __expf(lg[e] - m1);
        const float w0 = 1.0f / s;
        const float w1 = __expf(m2 - m1) / s;
        int slot0 = atomicAdd(&counts[i1], 1);
        tok_list[i1 * T_TOK + slot0] = t;
        w_list[i1 * T_TOK + slot0] = w0;
        int slot1 = atomicAdd(&counts[i2], 1);
        tok_list[i2 * T_TOK + slot1] = t;
        w_list[i2 * T_TOK + slot1] = w1;
        se[0] = i1; se[1] = i2; sw[0] = w0; sw[1] = w1;
    }
    __syncthreads();
    const int e0 = se[0], e1 = se[1];
    const float w0 = sw[0], w1 = sw[1];
    const int c = tid * 4;
    float4 d0 = *(const float4*)(db + e0 * H_DIM + c);
    float4 d1 = *(const float4*)(db + e1 * H_DIM + c);
    float4 o;
    o.x = w0 * d0.x + w1 * d1.x;
    o.y = w0 * d0.y + w1 * d1.y;
    o.z = w0 * d0.z + w1 * d1.z;
    o.w = w0 * d0.w + w1 * d1.w;
    *(float4*)(out + (size_t)t * H_DIM + c) = o;
}

// ------------- K2: weight fp32 -> bf16 transposed [e][col][k] ---------------
// 64x64 tiles via LDS (xor-swizzled dword groups, conflict-free both phases).
// bid < 4096: gup tile; else dp tile.
__global__ __launch_bounds__(256) void k_prep(
    const float* __restrict__ gup, const float* __restrict__ dp,
    u16* __restrict__ gup_t, u16* __restrict__ dp_t)
{
    __shared__ unsigned Lt[64 * 36];
    const int bid = blockIdx.x;
    const float* src; u16* dst; int C, ct, kt;
    if (bid < 4096) {
        int e = bid >> 9, t = bid & 511;
        ct = t & 31; kt = t >> 5; C = 2048;
        src = gup + ((size_t)e << 21);
        dst = gup_t + ((size_t)e << 21);
    } else {
        int b2 = bid - 4096;
        int e = b2 >> 8, t = b2 & 255;
        ct = t & 15; kt = t >> 4; C = 1024;
        src = dp + ((size_t)e << 20);
        dst = dp_t + ((size_t)e << 20);
    }
    const int k0 = kt * 64, c0 = ct * 64;
    const int tid = threadIdx.x;

    // read: k-pair rows (2kp, 2kp+1), col octet q*8
    const int kp = tid >> 3, q = tid & 7;
    const float* s0 = src + (size_t)(k0 + 2 * kp) * C + c0 + q * 8;
    float4 r0a = *(const float4*)(s0);
    float4 r0b = *(const float4*)(s0 + 4);
    float4 r1a = *(const float4*)(s0 + C);
    float4 r1b = *(const float4*)(s0 + C + 4);
    const float* e0 = (const float*)&r0a;
    const float* e1 = (const float*)&r0b;
    const float* f0 = (const float*)&r1a;
    const float* f1 = (const float*)&r1b;
#pragma unroll
    for (int j = 0; j < 8; ++j) {
        float lo = (j < 4) ? e0[j] : e1[j - 4];
        float hi = (j < 4) ? f0[j] : f1[j - 4];
        int cl = q * 8 + j;
        int grp = (kp >> 2) ^ q;                 // xor-swizzle dword group
        Lt[cl * 36 + (grp << 2) + (kp & 3)] = pk2(lo, hi);
    }
    __syncthreads();

    // write: col cl = tid>>2, two k-octets ko2*2, ko2*2+1
    const int cl = tid >> 2, ko2 = tid & 3;
#pragma unroll
    for (int i = 0; i < 2; ++i) {
        int koct = ko2 * 2 + i;
        int grp = koct ^ (cl >> 3);
        uint4 v = *(const uint4*)&Lt[cl * 36 + (grp << 2)];
        *(uint4*)(dst + (size_t)(c0 + cl) * 1024 + k0 + koct * 8) = v;
    }
}

// --------------------------- K3: gate_up GEMM + GLU -------------------------
// tile 128 rows x (32 gate + 32 up), BK=64, LDS dbuf, PF reg distance 2;
// grid (32 strips, 8 m, 8 e). B is bf16 transposed: staging = uint4 copies.
__global__ __launch_bounds__(256) void k_gateup(
    const u16* __restrict__ gup_t, const float* __restrict__ gub,
    const int* __restrict__ counts, const int* __restrict__ tok_list,
    const u16* __restrict__ xb, u16* __restrict__ act)
{
    const int e = blockIdx.z;
    int cnt, abase;
    expert_range(counts, e, cnt, abase);
    const int m0 = blockIdx.y * 128;
    if (m0 >= cnt) return;
    const int n0 = blockIdx.x * 32;
    const int tid = threadIdx.x;

    __shared__ __align__(16) u16 As[2][128 * LSTR];   // 2 x 18.4 KB
    __shared__ __align__(16) u16 Bs[2][64 * LSTR];    // rows 0..31 gate, 32..63 up

    // A staging: row = tid>>1, k-half = (tid&1)*32 -> 4 uint4 / chunk
    const int arow_i = tid >> 1, akh = (tid & 1) * 32;
    const int aslot = m0 + arow_i;
    const int atok = (aslot < cnt) ? tok_list[e * T_TOK + aslot] : 0;
    const u16* asrc = xb + (size_t)atok * H_DIM + akh;
    const int aoff = arow_i * LSTR + akh;

    // B staging: col cl = tid>>3 (0..31), k-octet koct = tid&7 -> 2 uint4
    const int cl = tid >> 3, koct = tid & 7;
    const u16* bgs = gup_t + ((size_t)(e * 2048 + n0 + cl)) * 1024 + koct * 8;
    const u16* bus = bgs + (size_t)1024 * 1024;   // up cols are +1024 rows
    const int boffg = cl * LSTR + koct * 8;
    const int boffu = (32 + cl) * LSTR + koct * 8;

    const int lane = tid & 63, wv = tid >> 6;
    const int fm = lane & 15, kg = lane >> 4;

    f32x4 accg[2][2], accu[2][2];
#pragma unroll
    for (int mt = 0; mt < 2; ++mt)
#pragma unroll
        for (int nt = 0; nt < 2; ++nt) {
            accg[mt][nt] = (f32x4){0.f, 0.f, 0.f, 0.f};
            accu[mt][nt] = (f32x4){0.f, 0.f, 0.f, 0.f};
        }

#define GU_LOAD(A0, A1, A2, A3, G, U, CH)                                      \
    {                                                                          \
        const u16* ap_ = asrc + (CH) * 64;                                     \
        A0 = *(const uint4*)(ap_);                                             \
        A1 = *(const uint4*)(ap_ + 8);                                         \
        A2 = *(const uint4*)(ap_ + 16);                                        \
        A3 = *(const uint4*)(ap_ + 24);                                        \
        G = *(const uint4*)(bgs + (CH) * 64);                                  \
        U = *(const uint4*)(bus + (CH) * 64);                                  \
    }
#define GU_STORE(BUF, A0, A1, A2, A3, G, U)                                    \
    {                                                                          \
        *(uint4*)&As[BUF][aoff]      = A0;                                     \
        *(uint4*)&As[BUF][aoff + 8]  = A1;                                     \
        *(uint4*)&As[BUF][aoff + 16] = A2;                                     \
        *(uint4*)&As[BUF][aoff + 24] = A3;                                     \
        *(uint4*)&Bs[BUF][boffg] = G;                                          \
        *(uint4*)&Bs[BUF][boffu] = U;                                          \
    }
#define GU_MFMA(BUF)                                                           \
    {                                                                          \
        _Pragma("unroll")                                                      \
        for (int sub = 0; sub < 2; ++sub) {                                    \
            _Pragma("unroll")                                                  \
            for (int mt = 0; mt < 2; ++mt) {                                   \
                bf16x8 af = *(const bf16x8*)&As[BUF][(wv * 32 + mt * 16 + fm) * LSTR + sub * 32 + kg * 8]; \
                _Pragma("unroll")                                              \
                for (int nt = 0; nt < 2; ++nt) {                               \
                    bf16x8 bg = *(const bf16x8*)&Bs[BUF][(nt * 16 + fm) * LSTR + sub * 32 + kg * 8]; \
                    bf16x8 bu = *(const bf16x8*)&Bs[BUF][(32 + nt * 16 + fm) * LSTR + sub * 32 + kg * 8]; \
                    accg[mt][nt] = mfma16(af, bg, accg[mt][nt]);               \
                    accu[mt][nt] = mfma16(af, bu, accu[mt][nt]);               \
                }                                                              \
            }                                                                  \
        }                                                                      \
    }

    uint4 A0r0, A1r0, A2r0, A3r0, Gr0, Ur0;
    uint4 A0r1, A1r1, A2r1, A3r1, Gr1, Ur1;
    GU_LOAD(A0r0, A1r0, A2r0, A3r0, Gr0, Ur0, 0);
    GU_LOAD(A0r1, A1r1, A2r1, A3r1, Gr1, Ur1, 1);
    GU_STORE(0, A0r0, A1r0, A2r0, A3r0, Gr0, Ur0);
    GU_LOAD(A0r0, A1r0, A2r0, A3r0, Gr0, Ur0, 2);

#pragma unroll 4
    for (int i = 0; i < 16; ++i) {
        __syncthreads();
        const int b = i & 1;
        if (i < 15) {
            if (b == 0) { GU_STORE(1, A0r1, A1r1, A2r1, A3r1, Gr1, Ur1); }
            else        { GU_STORE(0, A0r0, A1r0, A2r0, A3r0, Gr0, Ur0); }
        }
        if (i < 13) {
            if (b == 0) { GU_LOAD(A0r1, A1r1, A2r1, A3r1, Gr1, Ur1, i + 3); }
            else        { GU_LOAD(A0r0, A1r0, A2r0, A3r0, Gr0, Ur0, i + 3); }
        }
        GU_MFMA(b);
    }
#undef GU_LOAD
#undef GU_STORE
#undef GU_MFMA

    // epilogue: bias + clamped GLU -> compact bf16 act rows
#pragma unroll
    for (int mt = 0; mt < 2; ++mt) {
#pragma unroll
        for (int r = 0; r < 4; ++r) {
            int rowb = wv * 32 + mt * 16 + kg * 4 + r;  // C/D row=(lane>>4)*4+reg
            int slot = m0 + rowb;
            if (slot >= cnt) continue;
            size_t arow_o = (size_t)(abase + slot) * I_DIM;
#pragma unroll
            for (int nt = 0; nt < 2; ++nt) {
                int cn = n0 + nt * 16 + fm;             // C/D col=lane&15
                float g = accg[mt][nt][r] + gub[e * 2048 + cn];
                float u = accu[mt][nt][r] + gub[e * 2048 + 1024 + cn];
                g = fminf(g, LIMIT);
                u = fminf(fmaxf(u, -LIMIT), LIMIT);
                float glu = g / (1.f + __expf(-ALPHA * g));
                act[arow_o + cn] = f2bf((u + 1.f) * glu);
            }
        }
    }
}

// ------------- K4: down GEMM * w, atomic combine into out -------------------
// tile 128 rows x 64 cols, K-split 2, BK=64, LDS dbuf, PF distance 2;
// grid (16 strips, 8 m, 8 e * 2 ks).
__global__ __launch_bounds__(256) void k_down(
    const u16* __restrict__ dp_t,
    const int* __restrict__ counts, const int* __restrict__ tok_list,
    const float* __restrict__ w_list,
    const u16* __restrict__ act, float* __restrict__ out)
{
    const int e = blockIdx.z & 7, ks = blockIdx.z >> 3;
    int cnt, abase;
    expert_range(counts, e, cnt, abase);
    const int m0 = blockIdx.y * 128;
    if (m0 >= cnt) return;
    const int n0 = blockIdx.x * 64;
    const int tid = threadIdx.x;

    __shared__ __align__(16) u16 As[2][128 * LSTR];
    __shared__ __align__(16) u16 Bs[2][64 * LSTR];

    const int arow_i = tid >> 1, akh = (tid & 1) * 32;
    // rows past cnt read slack rows (finite), masked at store
    const u16* asrc = act + (size_t)(abase + m0 + arow_i) * I_DIM + ks * 512 + akh;
    const int aoff = arow_i * LSTR + akh;

    const int cl = tid >> 3, koct = tid & 7;
    const u16* bs0 = dp_t + ((size_t)(e * 1024 + n0 + cl)) * 1024 + ks * 512 + koct * 8;
    const u16* bs1 = bs0 + (size_t)32 * 1024;     // cols +32
    const int boff0 = cl * LSTR + koct * 8;
    const int boff1 = (32 + cl) * LSTR + koct * 8;

    const int lane = tid & 63, wv = tid >> 6;
    const int fm = lane & 15, kg = lane >> 4;

    f32x4 acc[2][4];
#pragma unroll
    for (int mt = 0; mt < 2; ++mt)
#pragma unroll
        for (int nt = 0; nt < 4; ++nt) acc[mt][nt] = (f32x4){0.f, 0.f, 0.f, 0.f};

#define DN_LOAD(A0, A1, A2, A3, B0, B1, CH)                                    \
    {                                                                          \
        const u16* ap_ = asrc + (CH) * 64;                                     \
        A0 = *(const uint4*)(ap_);                                             \
        A1 = *(const uint4*)(ap_ + 8);                                         \
        A2 = *(const uint4*)(ap_ + 16);                                        \
        A3 = *(const uint4*)(ap_ + 24);                                        \
        B0 = *(const uint4*)(bs0 + (CH) * 64);                                 \
        B1 = *(const uint4*)(bs1 + (CH) * 64);                                 \
    }
#define DN_STORE(BUF, A0, A1, A2, A3, B0, B1)                                  \
    {                                                                          \
        *(uint4*)&As[BUF][aoff]      = A0;                                     \
        *(uint4*)&As[BUF][aoff + 8]  = A1;                                     \
        *(uint4*)&As[BUF][aoff + 16] = A2;                                     \
        *(uint4*)&As[BUF][aoff + 24] = A3;                                     \
        *(uint4*)&Bs[BUF][boff0] = B0;                                         \
        *(uint4*)&Bs[BUF][boff1] = B1;                                         \
    }
#define DN_MFMA(BUF)                                                           \
    {                                                                          \
        _Pragma("unroll")                                                      \
        for (int sub = 0; sub < 2; ++sub) {                                    \
            _Pragma("unroll")                                                  \
            for (int mt = 0; mt < 2; ++mt) {                                   \
                bf16x8 af = *(const bf16x8*)&As[BUF][(wv * 32 + mt * 16 + fm) * LSTR + sub * 32 + kg * 8]; \
                _Pragma("unroll")                                              \
                for (int nt = 0; nt < 4; ++nt) {                               \
                    bf16x8 bb = *(const bf16x8*)&Bs[BUF][(nt * 16 + fm) * LSTR + sub * 32 + kg * 8]; \
                    acc[mt][nt] = mfma16(af, bb, acc[mt][nt]);                 \
                }                                                              \
            }                                                                  \
        }                                                                      \
    }

    uint4 A0r0, A1r0, A2r0, A3r0, B0r0, B1r0;
    uint4 A0r1, A1r1, A2r1, A3r1, B0r1, B1r1;
    DN_LOAD(A0r0, A1r0, A2r0, A3r0, B0r0, B1r0, 0);
    DN_LOAD(A0r1, A1r1, A2r1, A3r1, B0r1, B1r1, 1);
    DN_STORE(0, A0r0, A1r0, A2r0, A3r0, B0r0, B1r0);
    DN_LOAD(A0r0, A1r0, A2r0, A3r0, B0r0, B1r0, 2);

#pragma unroll 4
    for (int i = 0; i < 8; ++i) {
        __syncthreads();
        const int b = i & 1;
        if (i < 7) {
            if (b == 0) { DN_STORE(1, A0r1, A1r1, A2r1, A3r1, B0r1, B1r1); }
            else        { DN_STORE(0, A0r0, A1r0, A2r0, A3r0, B0r0, B1r0); }
        }
        if (i < 5) {
            if (b == 0) { DN_LOAD(A0r1, A1r1, A2r1, A3r1, B0r1, B1r1, i + 3); }
            else        { DN_LOAD(A0r0, A1r0, A2r0, A3r0, B0r0, B1r0, i + 3); }
        }
        DN_MFMA(b);
    }
#undef DN_LOAD
#undef DN_STORE
#undef DN_MFMA

#pragma unroll
    for (int mt = 0; mt < 2; ++mt) {
#pragma unroll
        for (int r = 0; r < 4; ++r) {
            int rowb = wv * 32 + mt * 16 + kg * 4 + r;
            int slot = m0 + rowb;
            if (slot >= cnt) continue;
            float wgt = w_list[e * T_TOK + slot];
            int tok = tok_list[e * T_TOK + slot];
            float* orow = out + (size_t)tok * H_DIM + n0;
#pragma unroll
            for (int nt = 0; nt < 4; ++nt)
                atomicAdd(orow + nt * 16 + fm, acc[mt][nt][r] * wgt);
        }
    }
}

// ---------------------------------------------------------------------------
extern "C" void kernel_launch(void* const* d_in, const int* in_sizes, int n_in,
                              void* d_out, int out_size, void* d_ws, size_t ws_size,
                              hipStream_t stream) {
    const float* x   = (const float*)d_in[0]; // [1,1024,1024]
    const float* rw  = (const float*)d_in[1]; // [8,1024]
    const float* rb  = (const float*)d_in[2]; // [8]
    const float* gup = (const float*)d_in[3]; // [8,1024,2048]
    const float* gub = (const float*)d_in[4]; // [8,2048]
    const float* dp  = (const float*)d_in[5]; // [8,1024,1024]
    const float* db  = (const float*)d_in[6]; // [8,1024]
    float* out = (float*)d_out;

    char* ws = (char*)d_ws;
    int*   counts   = (int*)(ws);                      // 64 B
    int*   tok_list = (int*)(ws + 64);                 // 32 KB
    float* w_list   = (float*)(ws + 32832);            // 32 KB
    u16*   xb       = (u16*)(ws + 65600);              // 2 MB
    u16*   gup_t    = (u16*)(ws + 2162752);            // 32 MB [e][2048c][1024k]
    u16*   dp_t     = (u16*)(ws + 35717184);           // 16 MB [e][1024c][1024k]
    u16*   act      = (u16*)(ws + 52494400);           // 2176*1024 bf16 (4.25 MB)

    hipMemsetAsync(counts, 0, 64, stream);
    k_router<<<T_TOK, 256, 0, stream>>>(x, rw, rb, db, counts, tok_list, w_list,
                                        xb, out);
    k_prep<<<6144, 256, 0, stream>>>(gup, dp, gup_t, dp_t);
    k_gateup<<<dim3(32, 8, 8), 256, 0, stream>>>(gup_t, gub, counts, tok_list,
                                                 xb, act);
    k_down<<<dim3(16, 8, 16), 256, 0, stream>>>(dp_t, counts, tok_list, w_list,
                                                act, out);
}